// Round 1
// baseline (130.265 us; speedup 1.0000x reference)
//
#include <hip/hip_runtime.h>
#include <hip/hip_bf16.h>

#define SS 4
#define CC 128
#define WELEM 18432   // per-(s,c) W chunk, bf16 elems: 16384 main [n][jl] + 2048 tail (B-frag)
#define NK3 23
#define NK2 5
#define NK1 2
#define DLP 72        // Dl row stride (ushorts); 144 B = 16B-aligned rows

typedef unsigned int uint;
typedef unsigned short ushort;
typedef __attribute__((ext_vector_type(8))) short bf16x8;
typedef __attribute__((ext_vector_type(4))) float f32x4;

__device__ __forceinline__ float bflo(uint u){ return __uint_as_float(u << 16); }
__device__ __forceinline__ float bfhi(uint u){ return __uint_as_float(u & 0xffff0000u); }
__device__ __forceinline__ ushort f2bf(float f) {
  uint u = __float_as_uint(f);
  return (ushort)((u + 0x7fffu + ((u >> 16) & 1u)) >> 16);
}
__device__ __forceinline__ uint pk2(float a, float b) {
  __hip_bfloat162 h = __float22bfloat162_rn(make_float2(a, b));  // v_cvt_pk_bf16_f32
  return *(uint*)&h;
}

// ============ pre_kernel: fold3 (blocks 0..511) + fold21 (512..1023) + sort (1024) ============
__global__ __launch_bounds__(256) void pre_kernel(
    const float* __restrict__ u3_0, const float* __restrict__ u3_1,
    const float* __restrict__ w3,
    const float* __restrict__ u2_0, const float* __restrict__ u2_1,
    const float* __restrict__ u1_0, const float* __restrict__ u1_1,
    const float* __restrict__ w2,  const float* __restrict__ w1,
    const int* __restrict__ sp, ushort* __restrict__ W,
    int* __restrict__ sorted, int* __restrict__ seg) {
  __shared__ float smem[5888];
  int bx = blockIdx.x;
  int tid = threadIdx.x;

  if (bx < 512) {
    // ---- fold3: W main, linear layout [s][c][n=o*16+i][jl], coalesced stores ----
    // w3 is wave-uniform (indices depend only on blockIdx + loop consts) -> read it
    // straight from global so the compiler emits s_load_dwordx4 (SMEM pipe) instead
    // of the old 16x ds_read_b128/k broadcast storm (1472 b128/block ~ 17K LDS-pipe
    // cycles/block, the previous bottleneck of this branch). u3 (per-lane) is
    // staged via LDS once and preloaded to 23 VGPRs.
    float* u3s = smem;            // 5888 floats
    int ch = bx & 1, i = (bx >> 1) & 15, o = (bx >> 5) & 3, s = bx >> 7;
    int g = (o > 0) ? 1 : 0, og = g ? (o - 1) : 0;
    const float* u3 = g ? u3_1 : u3_0;

    const float4* u3p = (const float4*)(u3 + (size_t)(og * 16 + i) * 5888);
    for (int d = tid; d < 1472; d += 256) {
      float4 v = u3p[d];
      u3s[4 * d] = v.x; u3s[4 * d + 1] = v.y; u3s[4 * d + 2] = v.z; u3s[4 * d + 3] = v.w;
    }
    __syncthreads();

    int jl = tid;
    float u3r[NK3];
    #pragma unroll
    for (int k = 0; k < NK3; k++) u3r[k] = u3s[jl * NK3 + k];

    const float* w3g = w3 + (size_t)(g * SS + s) * NK3 * CC + ch * 64;

    float acc[64];
    #pragma unroll
    for (int q = 0; q < 64; q++) acc[q] = 0.f;
    for (int k = 0; k < NK3; k++) {
      float u3v = u3r[k];
      const float4* wp = (const float4*)(w3g + (size_t)k * CC);
      #pragma unroll
      for (int cq = 0; cq < 16; cq++) {
        float4 wv = wp[cq];
        acc[cq * 4 + 0] = fmaf(u3v, wv.x, acc[cq * 4 + 0]);
        acc[cq * 4 + 1] = fmaf(u3v, wv.y, acc[cq * 4 + 1]);
        acc[cq * 4 + 2] = fmaf(u3v, wv.z, acc[cq * 4 + 2]);
        acc[cq * 4 + 3] = fmaf(u3v, wv.w, acc[cq * 4 + 3]);
      }
    }
    int n = o * 16 + i;
    #pragma unroll
    for (int cp = 0; cp < 64; cp++) {
      W[(size_t)(s * CC + ch * 64 + cp) * WELEM + n * 256 + jl] = f2bf(acc[cp]);
    }
  } else if (bx < 1024) {
    // ---- fold21: W tail (k=256..287), stored directly in B-frag layout ----
    int b2 = bx - 512;
    int s = b2 >> 7, c = b2 & 127;
    int n = tid >> 2, lq = tid & 3;
    int o = n >> 4, i = n & 15;
    int g = (o > 0) ? 1 : 0, og = g ? (o - 1) : 0;
    const float* u2 = g ? u2_1 : u2_0;
    const float* u1 = g ? u1_1 : u1_0;

    float vals[8];
    #pragma unroll
    for (int t = 0; t < 8; t++) {
      int k = 256 + lq * 8 + t;
      float v = 0.f;
      if (k < 272) {
        int j = k - 256;
        #pragma unroll
        for (int k2 = 0; k2 < NK2; k2++)
          v = fmaf(u2[((size_t)(og * 16 + i) * 16 + j) * NK2 + k2],
                   w2[((size_t)(g * SS + s) * NK2 + k2) * CC + c], v);
      } else if (k == 272) {
        #pragma unroll
        for (int k2 = 0; k2 < NK1; k2++)
          v = fmaf(u1[(size_t)(og * 16 + i) * NK1 + k2],
                   w1[((size_t)(g * SS + s) * NK1 + k2) * CC + c], v);
      }
      vals[t] = v;
    }
    uint4 pk;
    pk.x = pk2(vals[0], vals[1]); pk.y = pk2(vals[2], vals[3]);
    pk.z = pk2(vals[4], vals[5]); pk.w = pk2(vals[6], vals[7]);
    size_t base = (size_t)(s * CC + c) * WELEM;
    size_t off = 16384 + ((size_t)o * 64 + lq * 16 + i) * 8;
    *(uint4*)(W + base + off) = pk;
  } else {
    // ---- sort nodes by species ----
    __shared__ int cnt[SS];
    __shared__ int basep[SS + 1];
    if (tid < SS) cnt[tid] = 0;
    __syncthreads();
    int mysp[4], mypos[4];
    #pragma unroll
    for (int q = 0; q < 4; q++) {
      int node = q * 256 + tid;
      int s = sp[node];
      mysp[q] = s;
      mypos[q] = atomicAdd(&cnt[s], 1);
    }
    __syncthreads();
    if (tid == 0) {
      basep[0] = 0;
      for (int q = 0; q < SS; q++) basep[q + 1] = basep[q] + cnt[q];
      for (int q = 0; q <= SS; q++) seg[q] = basep[q];
    }
    __syncthreads();
    #pragma unroll
    for (int q = 0; q < 4; q++)
      sorted[basep[mysp[q]] + mypos[q]] = q * 256 + tid;
  }
}

// ============ corr_kernel: MFMA symmetric contraction ============
// grid 512 = s(4) x c(128); 4 waves; wave w owns rows [w*16,w*16+16) of each
// 64-node slab; a block now walks ALL slabs of its (s,c) segment (h-split merged:
// W is staged exactly once per (s,c) instead of twice, and the ~2K-cycle
// stage+barrier prologue is amortized over ~4 slabs instead of ~2; all 512 blocks
// are co-resident at 2/CU, so one block-round instead of two).
// x staged through wave-private LDS: one float4 per lane per slab.
// All B fragments in LDS. Epilogue via per-wave bf16 LDS transpose (no shfl).
// No __syncthreads in the loop: xl/Dl are wave-private, same-wave LDS ordering.
__global__ __launch_bounds__(256, 2) void corr_kernel(
    const float* __restrict__ xg, const ushort* __restrict__ Wg,
    const int* __restrict__ sorted, const int* __restrict__ seg,
    float* __restrict__ y) {
  __shared__ uint4 Wl4[2304];                       // 36 KB: kt0..7 swizzled + kt8 tail
  __shared__ __align__(16) float xl[4][16][20];     // 5 KB, per-wave region
  __shared__ __align__(16) ushort Dl[4 * 16 * DLP]; // 9 KB, per-wave region
  int bx = blockIdx.x;
  int s = bx >> 7, c = bx & 127;
  int tid = threadIdx.x;
  int w = tid >> 6, lane = tid & 63;
  int lq = lane >> 4, ln = lane & 15;

  const uint4* wg = (const uint4*)(Wg + (size_t)(s * CC + c) * WELEM);

  // stage Wl: main kt0..7 (xor-swizzled), coalesced global reads
  for (int d = tid; d < 2048; d += 256) {
    int n = d >> 5, j = d & 31;            // j = kt*4 + lqj
    int kt = j >> 2, lqj = j & 3;
    Wl4[(kt * 4 + (n >> 4)) * 64 + ((lqj * 16 + (n & 15)) ^ kt)] = wg[d];
  }
  // tail kt8 (flat; already in B-frag order from fold21)
  Wl4[2048 + tid] = wg[2048 + tid];

  int s0 = seg[s], s1 = seg[s + 1];
  int nslab = (s1 - s0 + 63) >> 6;

  // pre-stage x for slab 0: lane (lq,ln) loads chunk lq of row ln (16 B, no dup)
  int svcur = 0;
  if (nslab > 0) {
    int row = s0 + w * 16 + ln;
    svcur = sorted[min(row, s1 - 1)];
    float4 v = *((const float4*)(xg + ((size_t)svcur * CC + c) * 16) + lq);
    *(float4*)(&xl[w][ln][lq * 4]) = v;
  }
  __syncthreads();  // Wl ready (the only barrier)

  for (int kslab = 0; kslab < nslab; kslab++) {
    // own full row from wave-private LDS (4-way lq broadcast, 2-way ln alias: free)
    float xv[16];
    #pragma unroll
    for (int q = 0; q < 4; q++) {
      float4 v = *(const float4*)(&xl[w][ln][q * 4]);
      xv[q * 4] = v.x; xv[q * 4 + 1] = v.y; xv[q * 4 + 2] = v.z; xv[q * 4 + 3] = v.w;
    }
    int svc = svcur;
    int rowc = s0 + kslab * 64 + w * 16 + ln;
    // prefetch next slab x into 4 regs; LDS write deferred past the epilogue
    float4 xcn = make_float4(0.f, 0.f, 0.f, 0.f);
    int kn = kslab + 1;
    if (kn < nslab) {
      int row = s0 + kn * 64 + w * 16 + ln;
      svcur = sorted[min(row, s1 - 1)];
      xcn = *((const float4*)(xg + ((size_t)svcur * CC + c) * 16) + lq);
    }

    float xs8[8];
    #pragma unroll
    for (int t = 0; t < 8; t++) xs8[t] = (lq & 1) ? xv[8 + t] : xv[t];

    f32x4 acc[4];
    #pragma unroll
    for (int nt = 0; nt < 4; nt++) acc[nt] = (f32x4){0.f, 0.f, 0.f, 0.f};

    #pragma unroll
    for (int kt = 0; kt < 9; kt++) {
      uint4 av;
      if (kt < 8) {
        float xj = (lq & 2) ? xv[kt * 2 + 1] : xv[kt * 2];
        av.x = pk2(xj * xs8[0], xj * xs8[1]);
        av.y = pk2(xj * xs8[2], xj * xs8[3]);
        av.z = pk2(xj * xs8[4], xj * xs8[5]);
        av.w = pk2(xj * xs8[6], xj * xs8[7]);
      } else {
        av.x = pk2(xs8[0], xs8[1]);
        av.y = pk2(xs8[2], xs8[3]);
        av.z = pk2(xs8[4], xs8[5]);
        av.w = pk2(xs8[6], xs8[7]);
        if (lq == 2) av = make_uint4(0x3f80u, 0u, 0u, 0u);  // constant-1 column (k=272)
        if (lq == 3) av = make_uint4(0u, 0u, 0u, 0u);
      }
      bf16x8 a = *(bf16x8*)&av;
      #pragma unroll
      for (int nt = 0; nt < 4; nt++) {
        uint4 bv;
        if (kt < 8) {
          bv = Wl4[(kt * 4 + nt) * 64 + (lane ^ kt)];
        } else {
          bv = Wl4[2048 + nt * 64 + lane];
        }
        bf16x8 b = *(bf16x8*)&bv;
        acc[nt] = __builtin_amdgcn_mfma_f32_16x16x32_bf16(a, b, acc[nt], 0, 0, 0);
      }
    }

    // epilogue: per-wave LDS transpose of D (bf16), then lane (m=ln, o=lq)
    // reduces with its own xv (same row). C/D layout: row=lq*4+r, col=ln.
    #pragma unroll
    for (int nt = 0; nt < 4; nt++)
      #pragma unroll
      for (int r = 0; r < 4; r++)
        Dl[(w * 16 + lq * 4 + r) * DLP + nt * 16 + ln] = f2bf(acc[nt][r]);
    // same-wave write->read: compiler orders via lgkmcnt (LDS alias)
    const uint4* dp = (const uint4*)&Dl[(w * 16 + ln) * DLP + lq * 16];
    uint4 d0 = dp[0], d1 = dp[1];
    float r = 0.f;
    r = fmaf(bflo(d0.x), xv[0],  r); r = fmaf(bfhi(d0.x), xv[1],  r);
    r = fmaf(bflo(d0.y), xv[2],  r); r = fmaf(bfhi(d0.y), xv[3],  r);
    r = fmaf(bflo(d0.z), xv[4],  r); r = fmaf(bfhi(d0.z), xv[5],  r);
    r = fmaf(bflo(d0.w), xv[6],  r); r = fmaf(bfhi(d0.w), xv[7],  r);
    r = fmaf(bflo(d1.x), xv[8],  r); r = fmaf(bfhi(d1.x), xv[9],  r);
    r = fmaf(bflo(d1.y), xv[10], r); r = fmaf(bfhi(d1.y), xv[11], r);
    r = fmaf(bflo(d1.z), xv[12], r); r = fmaf(bfhi(d1.z), xv[13], r);
    r = fmaf(bflo(d1.w), xv[14], r); r = fmaf(bfhi(d1.w), xv[15], r);
    if (rowc < s1)
      y[((size_t)svc * CC + c) * 4 + lq] = r;

    // write prefetched x into wave-private xl (after xv/epilogue reads)
    if (kn < nslab)
      *(float4*)(&xl[w][ln][lq * 4]) = xcn;
  }
}

// ============ lin_kernel: channel-mixing linear + pack ============
// grid 1024 (one node each) x 128 threads (n)
__global__ __launch_bounds__(128) void lin_kernel(
    const float* __restrict__ y, const float* __restrict__ w_lin,
    float* __restrict__ out) {
  int b = blockIdx.x;
  int n = threadIdx.x;
  const float4* yb4 = (const float4*)(y + (size_t)b * 512);
  float a0 = 0.f, a1 = 0.f, a2 = 0.f, a3 = 0.f;
  #pragma unroll 8
  for (int cc = 0; cc < CC; cc++) {
    float4 yv = yb4[cc];                        // uniform broadcast
    float wl0 = w_lin[(size_t)cc * CC + n];     // g=0
    float wl1 = w_lin[16384 + (size_t)cc * CC + n];
    a0 = fmaf(yv.x, wl0, a0);
    a1 = fmaf(yv.y, wl1, a1);
    a2 = fmaf(yv.z, wl1, a2);
    a3 = fmaf(yv.w, wl1, a3);
  }
  const float scale = 0.08838834764831845f;  // 1/sqrt(128)
  out[(size_t)b * 512 + n] = a0 * scale;
  out[(size_t)b * 512 + 128 + (size_t)n * 3 + 0] = a1 * scale;
  out[(size_t)b * 512 + 128 + (size_t)n * 3 + 1] = a2 * scale;
  out[(size_t)b * 512 + 128 + (size_t)n * 3 + 2] = a3 * scale;
}

extern "C" void kernel_launch(void* const* d_in, const int* in_sizes, int n_in,
                              void* d_out, int out_size, void* d_ws, size_t ws_size,
                              hipStream_t stream) {
  const float* node_feats = (const float*)d_in[0];
  const float* u3_0 = (const float*)d_in[1];
  const float* u3_1 = (const float*)d_in[2];
  const float* u2_0 = (const float*)d_in[3];
  const float* u2_1 = (const float*)d_in[4];
  const float* u1_0 = (const float*)d_in[5];
  const float* u1_1 = (const float*)d_in[6];
  const float* w3   = (const float*)d_in[7];
  const float* w2   = (const float*)d_in[8];
  const float* w1   = (const float*)d_in[9];
  const float* wlin = (const float*)d_in[10];
  const int* species = (const int*)d_in[11];
  float* out = (float*)d_out;

  char* ws = (char*)d_ws;
  ushort* W  = (ushort*)ws;                  // 512*18432*2 = 18,874,368 B
  float* yb  = (float*)(ws + 18874368);      //  2,097,152 B
  int* sorted = (int*)(ws + 20971520);       //      4,096 B
  int* seg    = (int*)(ws + 20975616);       //         32 B

  pre_kernel<<<1025, 256, 0, stream>>>(u3_0, u3_1, w3, u2_0, u2_1, u1_0, u1_1,
                                       w2, w1, species, W, sorted, seg);
  corr_kernel<<<512, 256, 0, stream>>>(node_feats, W, sorted, seg, yb);
  lin_kernel<<<1024, 128, 0, stream>>>(yb, wlin, out);
}

// Round 2
// 121.734 us; speedup vs baseline: 1.0701x; 1.0701x over previous
//
#include <hip/hip_runtime.h>
#include <hip/hip_bf16.h>

#define SS 4
#define CC 128
#define WELEM 18432   // per-(s,c) W chunk, bf16 elems: 16384 main [n][jl] + 2048 tail (B-frag)
#define NK3 23
#define NK2 5
#define NK1 2
#define DLP 72        // Dl row stride (ushorts); 144 B = 16B-aligned rows

typedef unsigned int uint;
typedef unsigned short ushort;
typedef __attribute__((ext_vector_type(8))) short bf16x8;
typedef __attribute__((ext_vector_type(4))) float f32x4;

__device__ __forceinline__ float bflo(uint u){ return __uint_as_float(u << 16); }
__device__ __forceinline__ float bfhi(uint u){ return __uint_as_float(u & 0xffff0000u); }
__device__ __forceinline__ ushort f2bf(float f) {
  uint u = __float_as_uint(f);
  return (ushort)((u + 0x7fffu + ((u >> 16) & 1u)) >> 16);
}
__device__ __forceinline__ uint pk2(float a, float b) {
  __hip_bfloat162 h = __float22bfloat162_rn(make_float2(a, b));  // v_cvt_pk_bf16_f32
  return *(uint*)&h;
}

// ============ pre_kernel: fold3 (blocks 0..511) + fold21 (512..1023) + sort (1024) ============
__global__ __launch_bounds__(256) void pre_kernel(
    const float* __restrict__ u3_0, const float* __restrict__ u3_1,
    const float* __restrict__ w3,
    const float* __restrict__ u2_0, const float* __restrict__ u2_1,
    const float* __restrict__ u1_0, const float* __restrict__ u1_1,
    const float* __restrict__ w2,  const float* __restrict__ w1,
    const int* __restrict__ sp, ushort* __restrict__ W,
    int* __restrict__ sorted, int* __restrict__ seg) {
  __shared__ float smem[5888 + NK3 * 64];
  int bx = blockIdx.x;
  int tid = threadIdx.x;

  if (bx < 512) {
    // ---- fold3: W main, linear layout [s][c][n=o*16+i][jl] ----
    // Register tile 2 jl x 32 ch per thread (was 1 x 64): same 1472 FMA/thread but
    // w3s ds_read_b128 count halves (8/k instead of 16/k + u3 read from regs) —
    // the LDS pipe (shared per CU) was carrying ~17 ops/k/thread at 1:4 LDS:FMA.
    // u3 values (2 jl x 23 k = 46) preloaded to VGPRs once.
    // Epilogue packs the jl-adjacent pair via v_cvt_pk_bf16_f32 -> coalesced
    // 4B stores (256 B/wave) instead of 2B element stores.
    float* u3s = smem;            // 5888 floats
    float* w3s = smem + 5888;     // 23*64 floats
    int ch = bx & 1, i = (bx >> 1) & 15, o = (bx >> 5) & 3, s = bx >> 7;
    int g = (o > 0) ? 1 : 0, og = g ? (o - 1) : 0;
    const float* u3 = g ? u3_1 : u3_0;

    const float4* u3p = (const float4*)(u3 + (size_t)(og * 16 + i) * 5888);
    for (int d = tid; d < 1472; d += 256) {
      float4 v = u3p[d];
      u3s[4 * d] = v.x; u3s[4 * d + 1] = v.y; u3s[4 * d + 2] = v.z; u3s[4 * d + 3] = v.w;
    }
    for (int t = tid; t < NK3 * 64; t += 256) {
      int k = t >> 6, cp = t & 63;
      w3s[t] = w3[((size_t)(g * SS + s) * NK3 + k) * CC + ch * 64 + cp];
    }
    __syncthreads();

    int jl0 = (tid & 127) * 2;      // this thread's two jl rows
    int cb  = (tid >> 7) * 32;      // this thread's 32-channel sub-block

    float u3r[2][NK3];
    #pragma unroll
    for (int r = 0; r < 2; r++)
      #pragma unroll
      for (int k = 0; k < NK3; k++)
        u3r[r][k] = u3s[(jl0 + r) * NK3 + k];

    float acc[2][32];
    #pragma unroll
    for (int r = 0; r < 2; r++)
      #pragma unroll
      for (int q = 0; q < 32; q++) acc[r][q] = 0.f;

    for (int k = 0; k < NK3; k++) {
      const float4* wp = (const float4*)&w3s[k * 64 + cb];  // wave-uniform broadcast
      float ua = u3r[0][k], ub = u3r[1][k];
      #pragma unroll
      for (int cq = 0; cq < 8; cq++) {
        float4 wv = wp[cq];
        acc[0][cq * 4 + 0] = fmaf(ua, wv.x, acc[0][cq * 4 + 0]);
        acc[0][cq * 4 + 1] = fmaf(ua, wv.y, acc[0][cq * 4 + 1]);
        acc[0][cq * 4 + 2] = fmaf(ua, wv.z, acc[0][cq * 4 + 2]);
        acc[0][cq * 4 + 3] = fmaf(ua, wv.w, acc[0][cq * 4 + 3]);
        acc[1][cq * 4 + 0] = fmaf(ub, wv.x, acc[1][cq * 4 + 0]);
        acc[1][cq * 4 + 1] = fmaf(ub, wv.y, acc[1][cq * 4 + 1]);
        acc[1][cq * 4 + 2] = fmaf(ub, wv.z, acc[1][cq * 4 + 2]);
        acc[1][cq * 4 + 3] = fmaf(ub, wv.w, acc[1][cq * 4 + 3]);
      }
    }
    int n = o * 16 + i;
    #pragma unroll
    for (int cq = 0; cq < 32; cq++) {
      uint p = pk2(acc[0][cq], acc[1][cq]);  // lo=jl0, hi=jl0+1 (little-endian)
      *(uint*)&W[(size_t)(s * CC + ch * 64 + cb + cq) * WELEM + n * 256 + jl0] = p;
    }
  } else if (bx < 1024) {
    // ---- fold21: W tail (k=256..287), stored directly in B-frag layout ----
    int b2 = bx - 512;
    int s = b2 >> 7, c = b2 & 127;
    int n = tid >> 2, lq = tid & 3;
    int o = n >> 4, i = n & 15;
    int g = (o > 0) ? 1 : 0, og = g ? (o - 1) : 0;
    const float* u2 = g ? u2_1 : u2_0;
    const float* u1 = g ? u1_1 : u1_0;

    float vals[8];
    #pragma unroll
    for (int t = 0; t < 8; t++) {
      int k = 256 + lq * 8 + t;
      float v = 0.f;
      if (k < 272) {
        int j = k - 256;
        #pragma unroll
        for (int k2 = 0; k2 < NK2; k2++)
          v = fmaf(u2[((size_t)(og * 16 + i) * 16 + j) * NK2 + k2],
                   w2[((size_t)(g * SS + s) * NK2 + k2) * CC + c], v);
      } else if (k == 272) {
        #pragma unroll
        for (int k2 = 0; k2 < NK1; k2++)
          v = fmaf(u1[(size_t)(og * 16 + i) * NK1 + k2],
                   w1[((size_t)(g * SS + s) * NK1 + k2) * CC + c], v);
      }
      vals[t] = v;
    }
    uint4 pk;
    pk.x = pk2(vals[0], vals[1]); pk.y = pk2(vals[2], vals[3]);
    pk.z = pk2(vals[4], vals[5]); pk.w = pk2(vals[6], vals[7]);
    size_t base = (size_t)(s * CC + c) * WELEM;
    size_t off = 16384 + ((size_t)o * 64 + lq * 16 + i) * 8;
    *(uint4*)(W + base + off) = pk;
  } else {
    // ---- sort nodes by species ----
    __shared__ int cnt[SS];
    __shared__ int basep[SS + 1];
    if (tid < SS) cnt[tid] = 0;
    __syncthreads();
    int mysp[4], mypos[4];
    #pragma unroll
    for (int q = 0; q < 4; q++) {
      int node = q * 256 + tid;
      int s = sp[node];
      mysp[q] = s;
      mypos[q] = atomicAdd(&cnt[s], 1);
    }
    __syncthreads();
    if (tid == 0) {
      basep[0] = 0;
      for (int q = 0; q < SS; q++) basep[q + 1] = basep[q] + cnt[q];
      for (int q = 0; q <= SS; q++) seg[q] = basep[q];
    }
    __syncthreads();
    #pragma unroll
    for (int q = 0; q < 4; q++)
      sorted[basep[mysp[q]] + mypos[q]] = q * 256 + tid;
  }
}

// ============ corr_kernel: MFMA symmetric contraction ============
// grid 1024 = h(2) x s(4) x c(128); 4 waves; wave w owns rows [w*16,w*16+16) of
// each 64-node slab; block h handles slabs h, h+2, ... of its (s,c) segment.
// (h-split kept: round-1 A/B showed merging to 512 blocks regressed — finer
// blocks balance the nslab=4-vs-5 segment tails and the 2x W re-read is
// L3-absorbed anyway.)
// x staged through wave-private LDS: one float4 per lane per slab.
// All B fragments in LDS. Epilogue via per-wave bf16 LDS transpose (no shfl).
// No __syncthreads in the loop: xl/Dl are wave-private, same-wave LDS ordering.
__global__ __launch_bounds__(256, 2) void corr_kernel(
    const float* __restrict__ xg, const ushort* __restrict__ Wg,
    const int* __restrict__ sorted, const int* __restrict__ seg,
    float* __restrict__ y) {
  __shared__ uint4 Wl4[2304];                       // 36 KB: kt0..7 swizzled + kt8 tail
  __shared__ __align__(16) float xl[4][16][20];     // 5 KB, per-wave region
  __shared__ __align__(16) ushort Dl[4 * 16 * DLP]; // 9 KB, per-wave region
  int bx = blockIdx.x;
  int h = bx >> 9, s = (bx >> 7) & 3, c = bx & 127;
  int tid = threadIdx.x;
  int w = tid >> 6, lane = tid & 63;
  int lq = lane >> 4, ln = lane & 15;

  const uint4* wg = (const uint4*)(Wg + (size_t)(s * CC + c) * WELEM);

  // stage Wl: main kt0..7 (xor-swizzled), coalesced global reads
  for (int d = tid; d < 2048; d += 256) {
    int n = d >> 5, j = d & 31;            // j = kt*4 + lqj
    int kt = j >> 2, lqj = j & 3;
    Wl4[(kt * 4 + (n >> 4)) * 64 + ((lqj * 16 + (n & 15)) ^ kt)] = wg[d];
  }
  // tail kt8 (flat; already in B-frag order from fold21)
  Wl4[2048 + tid] = wg[2048 + tid];

  int s0 = seg[s], s1 = seg[s + 1];
  int nslab = (s1 - s0 + 63) >> 6;

  // pre-stage x for slab h: lane (lq,ln) loads chunk lq of row ln (16 B, no dup)
  int svcur = 0;
  if (h < nslab) {
    int row = s0 + h * 64 + w * 16 + ln;
    svcur = sorted[min(row, s1 - 1)];
    float4 v = *((const float4*)(xg + ((size_t)svcur * CC + c) * 16) + lq);
    *(float4*)(&xl[w][ln][lq * 4]) = v;
  }
  __syncthreads();  // Wl ready (the only barrier)

  for (int kslab = h; kslab < nslab; kslab += 2) {
    // own full row from wave-private LDS (4-way lq broadcast, 2-way ln alias: free)
    float xv[16];
    #pragma unroll
    for (int q = 0; q < 4; q++) {
      float4 v = *(const float4*)(&xl[w][ln][q * 4]);
      xv[q * 4] = v.x; xv[q * 4 + 1] = v.y; xv[q * 4 + 2] = v.z; xv[q * 4 + 3] = v.w;
    }
    int svc = svcur;
    int rowc = s0 + kslab * 64 + w * 16 + ln;
    // prefetch next slab x into 4 regs; LDS write deferred past the epilogue
    float4 xcn = make_float4(0.f, 0.f, 0.f, 0.f);
    int kn = kslab + 2;
    if (kn < nslab) {
      int row = s0 + kn * 64 + w * 16 + ln;
      svcur = sorted[min(row, s1 - 1)];
      xcn = *((const float4*)(xg + ((size_t)svcur * CC + c) * 16) + lq);
    }

    float xs8[8];
    #pragma unroll
    for (int t = 0; t < 8; t++) xs8[t] = (lq & 1) ? xv[8 + t] : xv[t];

    f32x4 acc[4];
    #pragma unroll
    for (int nt = 0; nt < 4; nt++) acc[nt] = (f32x4){0.f, 0.f, 0.f, 0.f};

    #pragma unroll
    for (int kt = 0; kt < 9; kt++) {
      uint4 av;
      if (kt < 8) {
        float xj = (lq & 2) ? xv[kt * 2 + 1] : xv[kt * 2];
        av.x = pk2(xj * xs8[0], xj * xs8[1]);
        av.y = pk2(xj * xs8[2], xj * xs8[3]);
        av.z = pk2(xj * xs8[4], xj * xs8[5]);
        av.w = pk2(xj * xs8[6], xj * xs8[7]);
      } else {
        av.x = pk2(xs8[0], xs8[1]);
        av.y = pk2(xs8[2], xs8[3]);
        av.z = pk2(xs8[4], xs8[5]);
        av.w = pk2(xs8[6], xs8[7]);
        if (lq == 2) av = make_uint4(0x3f80u, 0u, 0u, 0u);  // constant-1 column (k=272)
        if (lq == 3) av = make_uint4(0u, 0u, 0u, 0u);
      }
      bf16x8 a = *(bf16x8*)&av;
      #pragma unroll
      for (int nt = 0; nt < 4; nt++) {
        uint4 bv;
        if (kt < 8) {
          bv = Wl4[(kt * 4 + nt) * 64 + (lane ^ kt)];
        } else {
          bv = Wl4[2048 + nt * 64 + lane];
        }
        bf16x8 b = *(bf16x8*)&bv;
        acc[nt] = __builtin_amdgcn_mfma_f32_16x16x32_bf16(a, b, acc[nt], 0, 0, 0);
      }
    }

    // epilogue: per-wave LDS transpose of D (bf16), then lane (m=ln, o=lq)
    // reduces with its own xv (same row). C/D layout: row=lq*4+r, col=ln.
    #pragma unroll
    for (int nt = 0; nt < 4; nt++)
      #pragma unroll
      for (int r = 0; r < 4; r++)
        Dl[(w * 16 + lq * 4 + r) * DLP + nt * 16 + ln] = f2bf(acc[nt][r]);
    // same-wave write->read: compiler orders via lgkmcnt (LDS alias)
    const uint4* dp = (const uint4*)&Dl[(w * 16 + ln) * DLP + lq * 16];
    uint4 d0 = dp[0], d1 = dp[1];
    float r = 0.f;
    r = fmaf(bflo(d0.x), xv[0],  r); r = fmaf(bfhi(d0.x), xv[1],  r);
    r = fmaf(bflo(d0.y), xv[2],  r); r = fmaf(bfhi(d0.y), xv[3],  r);
    r = fmaf(bflo(d0.z), xv[4],  r); r = fmaf(bfhi(d0.z), xv[5],  r);
    r = fmaf(bflo(d0.w), xv[6],  r); r = fmaf(bfhi(d0.w), xv[7],  r);
    r = fmaf(bflo(d1.x), xv[8],  r); r = fmaf(bfhi(d1.x), xv[9],  r);
    r = fmaf(bflo(d1.y), xv[10], r); r = fmaf(bfhi(d1.y), xv[11], r);
    r = fmaf(bflo(d1.z), xv[12], r); r = fmaf(bfhi(d1.z), xv[13], r);
    r = fmaf(bflo(d1.w), xv[14], r); r = fmaf(bfhi(d1.w), xv[15], r);
    if (rowc < s1)
      y[((size_t)svc * CC + c) * 4 + lq] = r;

    // write prefetched x into wave-private xl (after xv/epilogue reads)
    if (kn < nslab)
      *(float4*)(&xl[w][ln][lq * 4]) = xcn;
  }
}

// ============ lin_kernel: channel-mixing linear + pack ============
// grid 1024 (one node each) x 128 threads (n)
__global__ __launch_bounds__(128) void lin_kernel(
    const float* __restrict__ y, const float* __restrict__ w_lin,
    float* __restrict__ out) {
  int b = blockIdx.x;
  int n = threadIdx.x;
  const float4* yb4 = (const float4*)(y + (size_t)b * 512);
  float a0 = 0.f, a1 = 0.f, a2 = 0.f, a3 = 0.f;
  #pragma unroll 8
  for (int cc = 0; cc < CC; cc++) {
    float4 yv = yb4[cc];                        // uniform broadcast
    float wl0 = w_lin[(size_t)cc * CC + n];     // g=0
    float wl1 = w_lin[16384 + (size_t)cc * CC + n];
    a0 = fmaf(yv.x, wl0, a0);
    a1 = fmaf(yv.y, wl1, a1);
    a2 = fmaf(yv.z, wl1, a2);
    a3 = fmaf(yv.w, wl1, a3);
  }
  const float scale = 0.08838834764831845f;  // 1/sqrt(128)
  out[(size_t)b * 512 + n] = a0 * scale;
  out[(size_t)b * 512 + 128 + (size_t)n * 3 + 0] = a1 * scale;
  out[(size_t)b * 512 + 128 + (size_t)n * 3 + 1] = a2 * scale;
  out[(size_t)b * 512 + 128 + (size_t)n * 3 + 2] = a3 * scale;
}

extern "C" void kernel_launch(void* const* d_in, const int* in_sizes, int n_in,
                              void* d_out, int out_size, void* d_ws, size_t ws_size,
                              hipStream_t stream) {
  const float* node_feats = (const float*)d_in[0];
  const float* u3_0 = (const float*)d_in[1];
  const float* u3_1 = (const float*)d_in[2];
  const float* u2_0 = (const float*)d_in[3];
  const float* u2_1 = (const float*)d_in[4];
  const float* u1_0 = (const float*)d_in[5];
  const float* u1_1 = (const float*)d_in[6];
  const float* w3   = (const float*)d_in[7];
  const float* w2   = (const float*)d_in[8];
  const float* w1   = (const float*)d_in[9];
  const float* wlin = (const float*)d_in[10];
  const int* species = (const int*)d_in[11];
  float* out = (float*)d_out;

  char* ws = (char*)d_ws;
  ushort* W  = (ushort*)ws;                  // 512*18432*2 = 18,874,368 B
  float* yb  = (float*)(ws + 18874368);      //  2,097,152 B
  int* sorted = (int*)(ws + 20971520);       //      4,096 B
  int* seg    = (int*)(ws + 20975616);       //         32 B

  pre_kernel<<<1025, 256, 0, stream>>>(u3_0, u3_1, w3, u2_0, u2_1, u1_0, u1_1,
                                       w2, w1, species, W, sorted, seg);
  corr_kernel<<<1024, 256, 0, stream>>>(node_feats, W, sorted, seg, yb);
  lin_kernel<<<1024, 128, 0, stream>>>(yb, wlin, out);
}

// Round 3
// 118.150 us; speedup vs baseline: 1.1025x; 1.0303x over previous
//
#include <hip/hip_runtime.h>
#include <hip/hip_bf16.h>

#define SS 4
#define CC 128
#define WELEM 18432   // per-(s,c) W chunk, bf16 elems: 16384 main [n][jl] + 2048 tail (B-frag)
#define NK3 23
#define NK2 5
#define NK1 2
#define DLP 72        // Dl row stride (ushorts); 144 B = 16B-aligned rows

typedef unsigned int uint;
typedef unsigned short ushort;
typedef __attribute__((ext_vector_type(8))) short bf16x8;
typedef __attribute__((ext_vector_type(4))) float f32x4;

__device__ __forceinline__ float bflo(uint u){ return __uint_as_float(u << 16); }
__device__ __forceinline__ float bfhi(uint u){ return __uint_as_float(u & 0xffff0000u); }
__device__ __forceinline__ ushort f2bf(float f) {
  uint u = __float_as_uint(f);
  return (ushort)((u + 0x7fffu + ((u >> 16) & 1u)) >> 16);
}
__device__ __forceinline__ uint pk2(float a, float b) {
  __hip_bfloat162 h = __float22bfloat162_rn(make_float2(a, b));  // v_cvt_pk_bf16_f32
  return *(uint*)&h;
}
// async global->LDS, 16 B/lane. HW semantics: LDS dest = wave-uniform base +
// lane*16 (pass a lane-invariant lds pointer); global src IS per-lane.
__device__ __forceinline__ void gload_lds16(const void* g, void* l) {
  __builtin_amdgcn_global_load_lds(
      (const __attribute__((address_space(1))) uint*)g,
      (__attribute__((address_space(3))) uint*)l, 16, 0, 0);
}

// ============ pre_kernel: fold3 (blocks 0..511) + fold21 (512..1023) + sort (1024) ============
__global__ __launch_bounds__(256) void pre_kernel(
    const float* __restrict__ u3_0, const float* __restrict__ u3_1,
    const float* __restrict__ w3,
    const float* __restrict__ u2_0, const float* __restrict__ u2_1,
    const float* __restrict__ u1_0, const float* __restrict__ u1_1,
    const float* __restrict__ w2,  const float* __restrict__ w1,
    const int* __restrict__ sp, ushort* __restrict__ W,
    int* __restrict__ sorted, int* __restrict__ seg) {
  __shared__ __align__(16) float smem[5888 + NK3 * 64];
  int bx = blockIdx.x;
  int tid = threadIdx.x;

  if (bx < 512) {
    // ---- fold3: W main, linear layout [s][c][n=o*16+i][jl] ----
    // Register tile 2 jl x 32 ch per thread; u3 values in 46 VGPRs; w3s reads are
    // wave-uniform broadcasts (free). u3 staged via global_load_lds (linear dest,
    // 6 issues/thread) instead of float4->4x ds_write_b32 (23 LDS writes/thread).
    float* u3s = smem;            // 5888 floats
    float* w3s = smem + 5888;     // 23*64 floats
    int ch = bx & 1, i = (bx >> 1) & 15, o = (bx >> 5) & 3, s = bx >> 7;
    int g = (o > 0) ? 1 : 0, og = g ? (o - 1) : 0;
    const float* u3 = g ? u3_1 : u3_0;

    const float4* u3p = (const float4*)(u3 + (size_t)(og * 16 + i) * 5888);
    #pragma unroll
    for (int it = 0; it < 6; it++) {
      int d = it * 256 + tid;
      if (d < 1472)
        gload_lds16(u3p + d, &u3s[4 * (it * 256 + (tid & 192))]);
    }
    for (int t = tid; t < NK3 * 64; t += 256) {
      int k = t >> 6, cp = t & 63;
      w3s[t] = w3[((size_t)(g * SS + s) * NK3 + k) * CC + ch * 64 + cp];
    }
    __syncthreads();   // drains vmcnt (global_load_lds) + lgkmcnt

    int jl0 = (tid & 127) * 2;      // this thread's two jl rows
    int cb  = (tid >> 7) * 32;      // this thread's 32-channel sub-block

    float u3r[2][NK3];
    #pragma unroll
    for (int r = 0; r < 2; r++)
      #pragma unroll
      for (int k = 0; k < NK3; k++)
        u3r[r][k] = u3s[(jl0 + r) * NK3 + k];

    float acc[2][32];
    #pragma unroll
    for (int r = 0; r < 2; r++)
      #pragma unroll
      for (int q = 0; q < 32; q++) acc[r][q] = 0.f;

    for (int k = 0; k < NK3; k++) {
      const float4* wp = (const float4*)&w3s[k * 64 + cb];  // wave-uniform broadcast
      float ua = u3r[0][k], ub = u3r[1][k];
      #pragma unroll
      for (int cq = 0; cq < 8; cq++) {
        float4 wv = wp[cq];
        acc[0][cq * 4 + 0] = fmaf(ua, wv.x, acc[0][cq * 4 + 0]);
        acc[0][cq * 4 + 1] = fmaf(ua, wv.y, acc[0][cq * 4 + 1]);
        acc[0][cq * 4 + 2] = fmaf(ua, wv.z, acc[0][cq * 4 + 2]);
        acc[0][cq * 4 + 3] = fmaf(ua, wv.w, acc[0][cq * 4 + 3]);
        acc[1][cq * 4 + 0] = fmaf(ub, wv.x, acc[1][cq * 4 + 0]);
        acc[1][cq * 4 + 1] = fmaf(ub, wv.y, acc[1][cq * 4 + 1]);
        acc[1][cq * 4 + 2] = fmaf(ub, wv.z, acc[1][cq * 4 + 2]);
        acc[1][cq * 4 + 3] = fmaf(ub, wv.w, acc[1][cq * 4 + 3]);
      }
    }
    int n = o * 16 + i;
    #pragma unroll
    for (int cq = 0; cq < 32; cq++) {
      uint p = pk2(acc[0][cq], acc[1][cq]);  // lo=jl0, hi=jl0+1 (little-endian)
      *(uint*)&W[(size_t)(s * CC + ch * 64 + cb + cq) * WELEM + n * 256 + jl0] = p;
    }
  } else if (bx < 1024) {
    // ---- fold21: W tail (k=256..287), stored directly in B-frag layout ----
    int b2 = bx - 512;
    int s = b2 >> 7, c = b2 & 127;
    int n = tid >> 2, lq = tid & 3;
    int o = n >> 4, i = n & 15;
    int g = (o > 0) ? 1 : 0, og = g ? (o - 1) : 0;
    const float* u2 = g ? u2_1 : u2_0;
    const float* u1 = g ? u1_1 : u1_0;

    float vals[8];
    #pragma unroll
    for (int t = 0; t < 8; t++) {
      int k = 256 + lq * 8 + t;
      float v = 0.f;
      if (k < 272) {
        int j = k - 256;
        #pragma unroll
        for (int k2 = 0; k2 < NK2; k2++)
          v = fmaf(u2[((size_t)(og * 16 + i) * 16 + j) * NK2 + k2],
                   w2[((size_t)(g * SS + s) * NK2 + k2) * CC + c], v);
      } else if (k == 272) {
        #pragma unroll
        for (int k2 = 0; k2 < NK1; k2++)
          v = fmaf(u1[(size_t)(og * 16 + i) * NK1 + k2],
                   w1[((size_t)(g * SS + s) * NK1 + k2) * CC + c], v);
      }
      vals[t] = v;
    }
    uint4 pk;
    pk.x = pk2(vals[0], vals[1]); pk.y = pk2(vals[2], vals[3]);
    pk.z = pk2(vals[4], vals[5]); pk.w = pk2(vals[6], vals[7]);
    size_t base = (size_t)(s * CC + c) * WELEM;
    size_t off = 16384 + ((size_t)o * 64 + lq * 16 + i) * 8;
    *(uint4*)(W + base + off) = pk;
  } else {
    // ---- sort nodes by species ----
    __shared__ int cnt[SS];
    __shared__ int basep[SS + 1];
    if (tid < SS) cnt[tid] = 0;
    __syncthreads();
    int mysp[4], mypos[4];
    #pragma unroll
    for (int q = 0; q < 4; q++) {
      int node = q * 256 + tid;
      int s = sp[node];
      mysp[q] = s;
      mypos[q] = atomicAdd(&cnt[s], 1);
    }
    __syncthreads();
    if (tid == 0) {
      basep[0] = 0;
      for (int q = 0; q < SS; q++) basep[q + 1] = basep[q] + cnt[q];
      for (int q = 0; q <= SS; q++) seg[q] = basep[q];
    }
    __syncthreads();
    #pragma unroll
    for (int q = 0; q < 4; q++)
      sorted[basep[mysp[q]] + mypos[q]] = q * 256 + tid;
  }
}

// ============ corr_kernel: MFMA symmetric contraction ============
// grid 1024 = h(2) x s(4) x c(128); 4 waves; wave w owns rows [w*16,w*16+16) of
// each 64-node slab; block h handles slabs h, h+2, ... of its (s,c) segment.
// (h-split kept: round-1 A/B showed merging to 512 blocks regressed.)
// W staged via global_load_lds: LDS dest is LINEAR (slot L = it*256+w*64+lane),
// the kt-xor swizzle is applied by INVERTING it on the per-lane GLOBAL source
// index (m173 both-sides-or-neither rule). Read side keeps the same xor.
// x staged through wave-private LDS; epilogue via per-wave bf16 LDS transpose.
// No __syncthreads in the loop: xl/Dl are wave-private, same-wave LDS ordering.
__global__ __launch_bounds__(256, 2) void corr_kernel(
    const float* __restrict__ xg, const ushort* __restrict__ Wg,
    const int* __restrict__ sorted, const int* __restrict__ seg,
    float* __restrict__ y) {
  __shared__ uint4 Wl4[2304];                       // 36 KB: kt0..7 swizzled + kt8 tail
  __shared__ __align__(16) float xl[4][16][20];     // 5 KB, per-wave region
  __shared__ __align__(16) ushort Dl[4 * 16 * DLP]; // 9 KB, per-wave region
  int bx = blockIdx.x;
  int h = bx >> 9, s = (bx >> 7) & 3, c = bx & 127;
  int tid = threadIdx.x;
  int w = tid >> 6, lane = tid & 63;
  int lq = lane >> 4, ln = lane & 15;

  const uint4* wg = (const uint4*)(Wg + (size_t)(s * CC + c) * WELEM);

  // stage Wl main kt0..7: slot L <- global chunk d(L) (inverse of the old
  // forward swizzle: L = (kt*4+q)*64 + ((lqj*16+nl)^kt), d = (q*16+nl)*32+kt*4+lqj)
  #pragma unroll
  for (int it = 0; it < 8; it++) {
    int L = it * 256 + tid;
    int kt = L >> 8, q = (L >> 6) & 3, mm = (L & 63) ^ kt;
    int d = (q * 16 + (mm & 15)) * 32 + kt * 4 + (mm >> 4);
    gload_lds16(wg + d, &Wl4[it * 256 + (tid & 192)]);
  }
  // tail kt8 (linear both sides; already in B-frag order from fold21)
  gload_lds16(wg + 2048 + tid, &Wl4[2048 + (tid & 192)]);

  int s0 = seg[s], s1 = seg[s + 1];
  int nslab = (s1 - s0 + 63) >> 6;

  // pre-stage x for slab h: lane (lq,ln) loads chunk lq of row ln (16 B, no dup)
  int svcur = 0;
  if (h < nslab) {
    int row = s0 + h * 64 + w * 16 + ln;
    svcur = sorted[min(row, s1 - 1)];
    float4 v = *((const float4*)(xg + ((size_t)svcur * CC + c) * 16) + lq);
    *(float4*)(&xl[w][ln][lq * 4]) = v;
  }
  __syncthreads();  // Wl ready: drains vmcnt(0) for global_load_lds (the only barrier)

  for (int kslab = h; kslab < nslab; kslab += 2) {
    // own full row from wave-private LDS (4-way lq broadcast, 2-way ln alias: free)
    float xv[16];
    #pragma unroll
    for (int q = 0; q < 4; q++) {
      float4 v = *(const float4*)(&xl[w][ln][q * 4]);
      xv[q * 4] = v.x; xv[q * 4 + 1] = v.y; xv[q * 4 + 2] = v.z; xv[q * 4 + 3] = v.w;
    }
    int svc = svcur;
    int rowc = s0 + kslab * 64 + w * 16 + ln;
    // prefetch next slab x into 4 regs; LDS write deferred past the epilogue
    float4 xcn = make_float4(0.f, 0.f, 0.f, 0.f);
    int kn = kslab + 2;
    if (kn < nslab) {
      int row = s0 + kn * 64 + w * 16 + ln;
      svcur = sorted[min(row, s1 - 1)];
      xcn = *((const float4*)(xg + ((size_t)svcur * CC + c) * 16) + lq);
    }

    float xs8[8];
    #pragma unroll
    for (int t = 0; t < 8; t++) xs8[t] = (lq & 1) ? xv[8 + t] : xv[t];

    f32x4 acc[4];
    #pragma unroll
    for (int nt = 0; nt < 4; nt++) acc[nt] = (f32x4){0.f, 0.f, 0.f, 0.f};

    #pragma unroll
    for (int kt = 0; kt < 9; kt++) {
      uint4 av;
      if (kt < 8) {
        float xj = (lq & 2) ? xv[kt * 2 + 1] : xv[kt * 2];
        av.x = pk2(xj * xs8[0], xj * xs8[1]);
        av.y = pk2(xj * xs8[2], xj * xs8[3]);
        av.z = pk2(xj * xs8[4], xj * xs8[5]);
        av.w = pk2(xj * xs8[6], xj * xs8[7]);
      } else {
        av.x = pk2(xs8[0], xs8[1]);
        av.y = pk2(xs8[2], xs8[3]);
        av.z = pk2(xs8[4], xs8[5]);
        av.w = pk2(xs8[6], xs8[7]);
        if (lq == 2) av = make_uint4(0x3f80u, 0u, 0u, 0u);  // constant-1 column (k=272)
        if (lq == 3) av = make_uint4(0u, 0u, 0u, 0u);
      }
      bf16x8 a = *(bf16x8*)&av;
      #pragma unroll
      for (int nt = 0; nt < 4; nt++) {
        uint4 bv;
        if (kt < 8) {
          bv = Wl4[(kt * 4 + nt) * 64 + (lane ^ kt)];
        } else {
          bv = Wl4[2048 + nt * 64 + lane];
        }
        bf16x8 b = *(bf16x8*)&bv;
        acc[nt] = __builtin_amdgcn_mfma_f32_16x16x32_bf16(a, b, acc[nt], 0, 0, 0);
      }
    }

    // epilogue: per-wave LDS transpose of D (bf16), then lane (m=ln, o=lq)
    // reduces with its own xv (same row). C/D layout: row=lq*4+r, col=ln.
    #pragma unroll
    for (int nt = 0; nt < 4; nt++)
      #pragma unroll
      for (int r = 0; r < 4; r++)
        Dl[(w * 16 + lq * 4 + r) * DLP + nt * 16 + ln] = f2bf(acc[nt][r]);
    // same-wave write->read: compiler orders via lgkmcnt (LDS alias)
    const uint4* dp = (const uint4*)&Dl[(w * 16 + ln) * DLP + lq * 16];
    uint4 d0 = dp[0], d1 = dp[1];
    float r = 0.f;
    r = fmaf(bflo(d0.x), xv[0],  r); r = fmaf(bfhi(d0.x), xv[1],  r);
    r = fmaf(bflo(d0.y), xv[2],  r); r = fmaf(bfhi(d0.y), xv[3],  r);
    r = fmaf(bflo(d0.z), xv[4],  r); r = fmaf(bfhi(d0.z), xv[5],  r);
    r = fmaf(bflo(d0.w), xv[6],  r); r = fmaf(bfhi(d0.w), xv[7],  r);
    r = fmaf(bflo(d1.x), xv[8],  r); r = fmaf(bfhi(d1.x), xv[9],  r);
    r = fmaf(bflo(d1.y), xv[10], r); r = fmaf(bfhi(d1.y), xv[11], r);
    r = fmaf(bflo(d1.z), xv[12], r); r = fmaf(bfhi(d1.z), xv[13], r);
    r = fmaf(bflo(d1.w), xv[14], r); r = fmaf(bfhi(d1.w), xv[15], r);
    if (rowc < s1)
      y[((size_t)svc * CC + c) * 4 + lq] = r;

    // write prefetched x into wave-private xl (after xv/epilogue reads)
    if (kn < nslab)
      *(float4*)(&xl[w][ln][lq * 4]) = xcn;
  }
}

// ============ lin_kernel: channel-mixing linear + pack ============
// grid 1024 (one node each) x 128 threads (n)
__global__ __launch_bounds__(128) void lin_kernel(
    const float* __restrict__ y, const float* __restrict__ w_lin,
    float* __restrict__ out) {
  int b = blockIdx.x;
  int n = threadIdx.x;
  const float4* yb4 = (const float4*)(y + (size_t)b * 512);
  float a0 = 0.f, a1 = 0.f, a2 = 0.f, a3 = 0.f;
  #pragma unroll 8
  for (int cc = 0; cc < CC; cc++) {
    float4 yv = yb4[cc];                        // uniform broadcast
    float wl0 = w_lin[(size_t)cc * CC + n];     // g=0
    float wl1 = w_lin[16384 + (size_t)cc * CC + n];
    a0 = fmaf(yv.x, wl0, a0);
    a1 = fmaf(yv.y, wl1, a1);
    a2 = fmaf(yv.z, wl1, a2);
    a3 = fmaf(yv.w, wl1, a3);
  }
  const float scale = 0.08838834764831845f;  // 1/sqrt(128)
  out[(size_t)b * 512 + n] = a0 * scale;
  out[(size_t)b * 512 + 128 + (size_t)n * 3 + 0] = a1 * scale;
  out[(size_t)b * 512 + 128 + (size_t)n * 3 + 1] = a2 * scale;
  out[(size_t)b * 512 + 128 + (size_t)n * 3 + 2] = a3 * scale;
}

extern "C" void kernel_launch(void* const* d_in, const int* in_sizes, int n_in,
                              void* d_out, int out_size, void* d_ws, size_t ws_size,
                              hipStream_t stream) {
  const float* node_feats = (const float*)d_in[0];
  const float* u3_0 = (const float*)d_in[1];
  const float* u3_1 = (const float*)d_in[2];
  const float* u2_0 = (const float*)d_in[3];
  const float* u2_1 = (const float*)d_in[4];
  const float* u1_0 = (const float*)d_in[5];
  const float* u1_1 = (const float*)d_in[6];
  const float* w3   = (const float*)d_in[7];
  const float* w2   = (const float*)d_in[8];
  const float* w1   = (const float*)d_in[9];
  const float* wlin = (const float*)d_in[10];
  const int* species = (const int*)d_in[11];
  float* out = (float*)d_out;

  char* ws = (char*)d_ws;
  ushort* W  = (ushort*)ws;                  // 512*18432*2 = 18,874,368 B
  float* yb  = (float*)(ws + 18874368);      //  2,097,152 B
  int* sorted = (int*)(ws + 20971520);       //      4,096 B
  int* seg    = (int*)(ws + 20975616);       //         32 B

  pre_kernel<<<1025, 256, 0, stream>>>(u3_0, u3_1, w3, u2_0, u2_1, u1_0, u1_1,
                                       w2, w1, species, W, sorted, seg);
  corr_kernel<<<1024, 256, 0, stream>>>(node_feats, W, sorted, seg, yb);
  lin_kernel<<<1024, 128, 0, stream>>>(yb, wlin, out);
}